// Round 10
// baseline (903.720 us; speedup 1.0000x reference)
//
#include <hip/hip_runtime.h>

#define HB 32
#define HT 256
#define HC 2048
#define HH 16
#define HD 128
#define HM (HB * HT)  // 8192

typedef __bf16 bf16x8 __attribute__((ext_vector_type(8)));
typedef float f32x4 __attribute__((ext_vector_type(4)));

__device__ __forceinline__ unsigned short f2bf(float f) {
  unsigned u = __float_as_uint(f);
  u += 0x7FFFu + ((u >> 16) & 1u);  // round-to-nearest-even
  return (unsigned short)(u >> 16);
}

// ---------------- fused fp32 -> bf16 convert (x + 4 weights) ----------------
__global__ __launch_bounds__(256) void cvt_all(
    const float* __restrict__ x, const float* __restrict__ wq, const float* __restrict__ wk,
    const float* __restrict__ wv, const float* __restrict__ wo,
    unsigned short* __restrict__ xb, unsigned short* __restrict__ wqb,
    unsigned short* __restrict__ wkb, unsigned short* __restrict__ wvb,
    unsigned short* __restrict__ wob) {
  size_t i = (size_t)blockIdx.x * 256 + threadIdx.x;
  const float* src;
  unsigned short* dst;
  size_t off;
  if (i < 4194304) {
    src = x; dst = xb; off = i;
  } else {
    size_t j = i - 4194304;
    int w = (int)(j >> 20);
    off = j & 1048575;
    src = (w == 0) ? wq : (w == 1) ? wk : (w == 2) ? wv : wo;
    dst = (w == 0) ? wqb : (w == 1) ? wkb : (w == 2) ? wvb : wob;
  }
  float4 v = ((const float4*)src)[off];
  ushort4 o;
  o.x = f2bf(v.x); o.y = f2bf(v.y); o.z = f2bf(v.z); o.w = f2bf(v.w);
  ((ushort4*)dst)[off] = o;
}

// ---------------- GEMM core: 128x256 tile, BK=64, A direct-from-global ----------------
// Round-9 closed the structure matrix: round-3 simple 2-barrier core is best and sits
// AT its LDS roofline (44.6% MfmaUtil == 768cyc LDS / 614cyc MFMA cap; conflicts 0).
// Round-10 lever: remove A from LDS. A-frags are read by only 2 waves/block -> load
// them global->register (attn r8 proved the batched-global-frag pattern), one K-tile
// ahead, ISSUED AFTER the post-stage barrier so the vmcnt(0) drain never waits on
// them (they get the full ~600cyc compute phase to land). LDS traffic -33% (B only:
// 512 cyc < 614 MFMA -> MFMA-bound). LDS 48->32 KB. B staging/swizzle byte-identical
// to verified round 3.
__device__ __forceinline__ void gl_lds16(const unsigned short* g, unsigned short* l) {
  __builtin_amdgcn_global_load_lds((const __attribute__((address_space(1))) void*)g,
                                   (__attribute__((address_space(3))) void*)l, 16, 0, 0);
}

// One K-tile step: stage B(kt) -> barrier -> prefetch A(ktp) to regs -> B ds_reads + MFMA.
// afu = A frags for THIS kt (already resident); afp = buffer to prefetch A(ktp) into.
__device__ __forceinline__ void gemm_step(const unsigned short* __restrict__ Arow,
                                          const unsigned short* __restrict__ Wb,
                                          unsigned short* lsB, f32x4 acc[4][8],
                                          bf16x8 afu[2][4], bf16x8 afp[2][4],
                                          int kt, int ktp, int tid, int ch, int wc, int l16) {
  __syncthreads();
  // stage B: [2 kh][256 rows][32] = 2048 x 16B chunks, swizzled source (round-3 verified)
#pragma unroll
  for (int i = 0; i < 8; i++) {
    int c = i * 256 + tid;
    int vrow = c >> 2, slot = c & 3;
    int gc = slot ^ ((vrow >> 1) & 3);
    int row = vrow & 255, kh = vrow >> 8;
    gl_lds16(Wb + (size_t)row * HC + kt * 64 + kh * 32 + gc * 8, lsB + c * 8);
  }
  __syncthreads();
  // A prefetch for ktp (global, 8 x b128). Issued after the drain-barrier: its
  // latency hides under this kt's ds_reads + 64 MFMAs; it is drained (for free,
  // already complete) by the NEXT step's pre-barrier vmcnt(0).
  if (ktp >= 0) {
#pragma unroll
    for (int kh = 0; kh < 2; kh++)
#pragma unroll
      for (int mi = 0; mi < 4; mi++)
        afp[kh][mi] = *(const bf16x8*)(Arow + (size_t)mi * (16 * HC) + ktp * 64 + kh * 32);
  }
#pragma unroll
  for (int kh = 0; kh < 2; ++kh) {
    bf16x8 bfr[8];
#pragma unroll
    for (int nj = 0; nj < 8; nj++) {
      int r = wc * 128 + nj * 16 + l16;
      bfr[nj] = *(const bf16x8*)(lsB + (kh * 256 + r) * 32 + ch);
    }
#pragma unroll
    for (int mi = 0; mi < 4; mi++)
#pragma unroll
      for (int nj = 0; nj < 8; nj++)
        acc[mi][nj] = __builtin_amdgcn_mfma_f32_16x16x32_bf16(afu[kh][mi], bfr[nj], acc[mi][nj], 0, 0, 0);
  }
}

// Per wave: 64x128 output = acc[4 m-frags][8 n-frags], 16x16x32 MFMA.
// C-layout (m89-verified): row = quad*4 + reg, col = l16.
// Ag = global A panel (row-major, stride HC); Wb = global W panel (staged to LDS).
__device__ __forceinline__ void gemm_core_wide(const unsigned short* __restrict__ Ag,
                                               const unsigned short* __restrict__ Wb,
                                               unsigned short* lsB,
                                               f32x4 acc[4][8], int tid) {
  const int lane = tid & 63, wave = tid >> 6;
  const int l16 = lane & 15, quad = lane >> 4;
  const int wr = wave >> 1, wc = wave & 1;
  const int ch = (quad ^ ((l16 >> 1) & 3)) * 8;
  // lane's A row base + k-chunk: af[kh][mi] = Ag[(wr*64+mi*16+l16)*HC + kt*64+kh*32+quad*8]
  const unsigned short* Arow = Ag + (size_t)(wr * 64 + l16) * HC + quad * 8;

  bf16x8 afA[2][4], afB[2][4];
#pragma unroll
  for (int kh = 0; kh < 2; kh++)
#pragma unroll
    for (int mi = 0; mi < 4; mi++)
      afA[kh][mi] = *(const bf16x8*)(Arow + (size_t)mi * (16 * HC) + kh * 32);

  // ping-pong register double-buffer (static indexing: rule-#20 safe)
  for (int kt = 0; kt < HC / 64; kt += 2) {
    gemm_step(Arow, Wb, lsB, acc, afA, afB, kt, kt + 1, tid, ch, wc, l16);
    gemm_step(Arow, Wb, lsB, acc, afB, afA, kt + 1, (kt + 2 < HC / 64) ? kt + 2 : -1,
              tid, ch, wc, l16);
  }
}

// Output projection GEMM: fp32 out [M, 2048]; grid (64, 8)
__global__ __launch_bounds__(256, 2) void gemm_out(const unsigned short* __restrict__ A,
                                                   const unsigned short* __restrict__ W,
                                                   float* __restrict__ outp) {
  __shared__ __align__(16) unsigned short lsB[2 * 256 * 32];
  const int tid = threadIdx.x;
  const int lane = tid & 63, wave = tid >> 6;
  const int l16 = lane & 15, quad = lane >> 4;
  const int wr = wave >> 1, wc = wave & 1;
  const int bm = blockIdx.x, bn = blockIdx.y;

  f32x4 acc[4][8];
#pragma unroll
  for (int i = 0; i < 4; i++)
#pragma unroll
    for (int j = 0; j < 8; j++) acc[i][j] = f32x4{0.f, 0.f, 0.f, 0.f};

  gemm_core_wide(A + (size_t)bm * 128 * HC, W + (size_t)bn * 256 * HC, lsB, acc, tid);

#pragma unroll
  for (int mi = 0; mi < 4; mi++)
#pragma unroll
    for (int nj = 0; nj < 8; nj++) {
      const int n = bn * 256 + wc * 128 + nj * 16 + l16;
#pragma unroll
      for (int rr = 0; rr < 4; rr++) {
        const int m = bm * 128 + wr * 64 + mi * 16 + quad * 4 + rr;
        outp[(size_t)m * HC + n] = acc[mi][nj][rr];
      }
    }
}

// Fused QKV GEMM: grid (64, 24); blockIdx.y>>3 selects {Q,K,V}.
// Q,K -> [B,H,T,D] with RoPE fused; V -> [B,H,D,T] via operand swap (coalesced).
__global__ __launch_bounds__(256, 2) void gemm_qkv(const unsigned short* __restrict__ A,
                                                    const unsigned short* __restrict__ W0,
                                                    const unsigned short* __restrict__ W1,
                                                    const unsigned short* __restrict__ W2,
                                                    unsigned short* __restrict__ Qo,
                                                    unsigned short* __restrict__ Ko,
                                                    unsigned short* __restrict__ Vto) {
  __shared__ __align__(16) unsigned short lsB[2 * 256 * 32];
  const int tid = threadIdx.x;
  const int lane = tid & 63, wave = tid >> 6;
  const int l16 = lane & 15, quad = lane >> 4;
  const int wr = wave >> 1, wc = wave & 1;
  const int bm = blockIdx.x;
  const int which = blockIdx.y >> 3;
  const int bn = blockIdx.y & 7;

  f32x4 acc[4][8];
#pragma unroll
  for (int i = 0; i < 4; i++)
#pragma unroll
    for (int j = 0; j < 8; j++) acc[i][j] = f32x4{0.f, 0.f, 0.f, 0.f};

  if (which < 2) {
    const unsigned short* W = (which == 0) ? W0 : W1;
    unsigned short* outp = (which == 0) ? Qo : Ko;
    gemm_core_wide(A + (size_t)bm * 128 * HC, W + (size_t)bn * 256 * HC, lsB, acc, tid);
    // Wave's 128 cols = one head: h = bn*2 + wc. RoPE pair: acc[mi][nj] (d) with
    // acc[mi][nj+4] (d+64), d = nj*16 + l16, nj in {0..3}.
    const int h = bn * 2 + wc;
#pragma unroll
    for (int nj = 0; nj < 4; nj++) {
      const int dlo = nj * 16 + l16;
      const float invf = __expf((float)dlo * (-0.14391156831212787f));
#pragma unroll
      for (int mi = 0; mi < 4; mi++)
#pragma unroll
        for (int rr = 0; rr < 4; rr++) {
          const int m = bm * 128 + wr * 64 + mi * 16 + quad * 4 + rr;
          const int t = m & 255, b = m >> 8;
          float ang = (float)t * invf;
          float sn, cs;
          __sincosf(ang, &sn, &cs);
          float lo = acc[mi][nj][rr], hi = acc[mi][nj + 4][rr];
          size_t base = (((size_t)b * HH + h) * HT + t) * HD;
          outp[base + dlo] = f2bf(lo * cs - hi * sn);
          outp[base + 64 + dlo] = f2bf(hi * cs + lo * sn);
        }
    }
  } else {
    // V^T: A-operand = wv channel tile (128 ch = one head, global-direct),
    // B-operand = x token tile (256, staged to LDS).
    int v = bn * 64 + bm;            // 512 blocks
    int tok = v & 31, ch2 = v >> 5;  // 32 token-tiles x 16 channel-tiles
    gemm_core_wide(W2 + (size_t)ch2 * 128 * HC, A + (size_t)tok * 256 * HC, lsB, acc, tid);
    const int b = tok, h = ch2;
#pragma unroll
    for (int mi = 0; mi < 4; mi++)
#pragma unroll
      for (int nj = 0; nj < 8; nj++) {
        const int t = wc * 128 + nj * 16 + l16;
#pragma unroll
        for (int rr = 0; rr < 4; rr++) {
          const int d = wr * 64 + mi * 16 + quad * 4 + rr;
          Vto[(((size_t)b * HH + h) * HD + d) * HT + t] = f2bf(acc[mi][nj][rr]);
        }
      }
  }
}

// ---------------- causal flash attention ----------------
// Round-8 body (K-load batching: ~+18us normalized win). Pairing {3,0}/{2,1} +
// T13 defer-max + ks=0 V-hoist + kf[4][2] batch retained. Do not touch.
__global__ __launch_bounds__(256) void attn_kernel(const unsigned short* __restrict__ Q,
                                                   const unsigned short* __restrict__ K,
                                                   const unsigned short* __restrict__ Vt,
                                                   unsigned short* __restrict__ Y) {
  const int g = blockIdx.x;      // 1024 blocks
  const int bh = g & 511;
  const int pairp = g >> 9;      // 0 -> {3,0}, 1 -> {2,1}
  const int wave = threadIdx.x >> 6;
  const int lane = threadIdx.x & 63;
  const int quad = lane >> 4, l16 = lane & 15;

  const unsigned short* Qh = Q + (size_t)bh * HT * HD;
  const unsigned short* Kh = K + (size_t)bh * HT * HD;
  const unsigned short* Vh = Vt + (size_t)bh * HD * HT;

  __shared__ __align__(16) unsigned short P[4][16 * 72];
  unsigned short* Pw = P[wave];

  const float scale = 0.088388347648318447f;  // 1/sqrt(128)
  const int b = bh >> 4, h = bh & 15;

  for (int half = 0; half < 2; ++half) {
    const int wq = (pairp == 0) ? (half == 0 ? 3 : 0) : (half == 0 ? 2 : 1);
    const int qrow = wq * 64 + wave * 16;

    bf16x8 qf[4];
#pragma unroll
    for (int ks = 0; ks < 4; ks++)
      qf[ks] = *(const bf16x8*)(Qh + (size_t)(qrow + l16) * HD + ks * 32 + quad * 8);

    f32x4 o[8];
#pragma unroll
    for (int di = 0; di < 8; di++) o[di] = f32x4{0.f, 0.f, 0.f, 0.f};
    float mrow[4], lrow[4];
#pragma unroll
    for (int r = 0; r < 4; r++) { mrow[r] = -1e30f; lrow[r] = 0.f; }

    for (int ct = 0; ct <= wq; ++ct) {
      f32x4 s[4];
#pragma unroll
      for (int ni = 0; ni < 4; ni++) s[ni] = f32x4{0.f, 0.f, 0.f, 0.f};
      const int nimax = (ct == wq) ? wave : 3;
      // QK^T in two half-K batches: issue 8 independent K loads, then 8 MFMAs.
#pragma unroll
      for (int ksh = 0; ksh < 2; ksh++) {
        bf16x8 kf[4][2];
#pragma unroll
        for (int ni = 0; ni < 4; ni++)
          if (ni <= nimax)
#pragma unroll
            for (int k2 = 0; k2 < 2; k2++)
              kf[ni][k2] = *(const bf16x8*)(Kh + (size_t)(ct * 64 + ni * 16 + l16) * HD +
                                            (ksh * 2 + k2) * 32 + quad * 8);
#pragma unroll
        for (int k2 = 0; k2 < 2; k2++)
#pragma unroll
          for (int ni = 0; ni < 4; ni++)
            if (ni <= nimax)
              s[ni] = __builtin_amdgcn_mfma_f32_16x16x32_bf16(qf[ksh * 2 + k2], kf[ni][k2],
                                                              s[ni], 0, 0, 0);
      }
      // T14 hoist: issue ks=0 half of the V tile now; latency hides under softmax.
      bf16x8 vf0[8];
#pragma unroll
      for (int di = 0; di < 8; di++)
        vf0[di] = *(const bf16x8*)(Vh + (size_t)(di * 16 + l16) * HT + ct * 64 + quad * 8);

      if (ct == wq) {
#pragma unroll
        for (int ni = 0; ni < 4; ni++)
#pragma unroll
          for (int r = 0; r < 4; r++) {
            int qr = wave * 16 + quad * 4 + r;
            int kc = ni * 16 + l16;
            s[ni][r] = (kc <= qr) ? s[ni][r] * scale : -1e30f;
          }
      } else {
#pragma unroll
        for (int ni = 0; ni < 4; ni++)
#pragma unroll
          for (int r = 0; r < 4; r++) s[ni][r] *= scale;
      }
      // per-row max (uniform within 16-lane group)
      float pm[4];
#pragma unroll
      for (int r = 0; r < 4; r++) {
        float v = fmaxf(fmaxf(s[0][r], s[1][r]), fmaxf(s[2][r], s[3][r]));
        v = fmaxf(v, __shfl_xor(v, 1, 64));
        v = fmaxf(v, __shfl_xor(v, 2, 64));
        v = fmaxf(v, __shfl_xor(v, 4, 64));
        v = fmaxf(v, __shfl_xor(v, 8, 64));
        pm[r] = v;
      }
      // T13 defer-max: wave-uniform rescale test (max growth across all 16 rows)
      float ex = fmaxf(fmaxf(pm[0] - mrow[0], pm[1] - mrow[1]),
                       fmaxf(pm[2] - mrow[2], pm[3] - mrow[3]));
      ex = fmaxf(ex, __shfl_xor(ex, 16, 64));
      ex = fmaxf(ex, __shfl_xor(ex, 32, 64));
      if (ex > 8.f) {
#pragma unroll
        for (int r = 0; r < 4; r++) {
          float mnew = fmaxf(mrow[r], pm[r]);
          float alpha = __expf(mrow[r] - mnew);
          mrow[r] = mnew;
          lrow[r] *= alpha;
#pragma unroll
          for (int di = 0; di < 8; di++) o[di][r] *= alpha;
        }
      }
#pragma unroll
      for (int r = 0; r < 4; r++) {
        float rs = 0.f;
#pragma unroll
        for (int ni = 0; ni < 4; ni++) {
          float e = __expf(s[ni][r] - mrow[r]);
          s[ni][r] = e;
          rs += e;
        }
        rs += __shfl_xor(rs, 1, 64);
        rs += __shfl_xor(rs, 2, 64);
        rs += __shfl_xor(rs, 4, 64);
        rs += __shfl_xor(rs, 8, 64);
        lrow[r] += rs;
      }
#pragma unroll
      for (int ni = 0; ni < 4; ni++)
#pragma unroll
        for (int r = 0; r < 4; r++)
          Pw[(quad * 4 + r) * 72 + ni * 16 + l16] = f2bf(s[ni][r]);
      // PV: ks=0 uses the hoisted vf0; ks=1 loads inline.
      {
        bf16x8 pf = *(const bf16x8*)(Pw + (size_t)l16 * 72 + quad * 8);
#pragma unroll
        for (int di = 0; di < 8; di++)
          o[di] = __builtin_amdgcn_mfma_f32_16x16x32_bf16(pf, vf0[di], o[di], 0, 0, 0);
      }
      {
        bf16x8 pf = *(const bf16x8*)(Pw + (size_t)l16 * 72 + 32 + quad * 8);
#pragma unroll
        for (int di = 0; di < 8; di++) {
          bf16x8 vf = *(const bf16x8*)(Vh + (size_t)(di * 16 + l16) * HT + ct * 64 + 32 + quad * 8);
          o[di] = __builtin_amdgcn_mfma_f32_16x16x32_bf16(pf, vf, o[di], 0, 0, 0);
        }
      }
    }

#pragma unroll
    for (int r = 0; r < 4; r++) {
      float inv = 1.f / lrow[r];
      int t = qrow + quad * 4 + r;
      size_t rowb = ((size_t)b * HT + t) * HC + h * HD;
#pragma unroll
      for (int di = 0; di < 8; di++)
        Y[rowb + di * 16 + l16] = f2bf(o[di][r] * inv);
    }
  }
}

// ---------------- launch ----------------
extern "C" void kernel_launch(void* const* d_in, const int* in_sizes, int n_in,
                              void* d_out, int out_size, void* d_ws, size_t ws_size,
                              hipStream_t stream) {
  const float* x  = (const float*)d_in[0];
  const float* wq = (const float*)d_in[1];
  const float* wk = (const float*)d_in[2];
  const float* wv = (const float*)d_in[3];
  const float* wo = (const float*)d_in[4];
  float* out = (float*)d_out;

  char* ws = (char*)d_ws;
  const size_t MB = (size_t)1 << 20;
  unsigned short* wqb = (unsigned short*)(ws + 0 * MB);
  unsigned short* wkb = (unsigned short*)(ws + 8 * MB);
  unsigned short* wvb = (unsigned short*)(ws + 16 * MB);
  unsigned short* wob = (unsigned short*)(ws + 24 * MB);
  unsigned short* xb  = (unsigned short*)(ws + 32 * MB);
  unsigned short* Qb  = (unsigned short*)(ws + 64 * MB);
  unsigned short* Kb  = (unsigned short*)(ws + 96 * MB);
  unsigned short* Vtb = (unsigned short*)(ws + 128 * MB);
  unsigned short* Yb  = xb;  // reuse x's bf16 buffer after QKV GEMMs

  cvt_all<<<32768, 256, 0, stream>>>(x, wq, wk, wv, wo, xb, wqb, wkb, wvb, wob);

  gemm_qkv<<<dim3(HM / 128, 24), 256, 0, stream>>>(xb, wqb, wkb, wvb, Qb, Kb, Vtb);

  attn_kernel<<<1024, 256, 0, stream>>>(Qb, Kb, Vtb, Yb);

  gemm_out<<<dim3(HM / 128, HC / 256), 256, 0, stream>>>(Yb, wob, out);
}

// Round 11
// 771.804 us; speedup vs baseline: 1.1709x; 1.1709x over previous
//
#include <hip/hip_runtime.h>

#define HB 32
#define HT 256
#define HC 2048
#define HH 16
#define HD 128
#define HM (HB * HT)  // 8192

typedef __bf16 bf16x8 __attribute__((ext_vector_type(8)));
typedef float f32x4 __attribute__((ext_vector_type(4)));

__device__ __forceinline__ unsigned short f2bf(float f) {
  unsigned u = __float_as_uint(f);
  u += 0x7FFFu + ((u >> 16) & 1u);  // round-to-nearest-even
  return (unsigned short)(u >> 16);
}

// ---------------- fused fp32 -> bf16 convert (x + 4 weights) ----------------
__global__ __launch_bounds__(256) void cvt_all(
    const float* __restrict__ x, const float* __restrict__ wq, const float* __restrict__ wk,
    const float* __restrict__ wv, const float* __restrict__ wo,
    unsigned short* __restrict__ xb, unsigned short* __restrict__ wqb,
    unsigned short* __restrict__ wkb, unsigned short* __restrict__ wvb,
    unsigned short* __restrict__ wob) {
  size_t i = (size_t)blockIdx.x * 256 + threadIdx.x;
  const float* src;
  unsigned short* dst;
  size_t off;
  if (i < 4194304) {
    src = x; dst = xb; off = i;
  } else {
    size_t j = i - 4194304;
    int w = (int)(j >> 20);
    off = j & 1048575;
    src = (w == 0) ? wq : (w == 1) ? wk : (w == 2) ? wv : wo;
    dst = (w == 0) ? wqb : (w == 1) ? wkb : (w == 2) ? wvb : wob;
  }
  float4 v = ((const float4*)src)[off];
  ushort4 o;
  o.x = f2bf(v.x); o.y = f2bf(v.y); o.z = f2bf(v.z); o.w = f2bf(v.w);
  ((ushort4*)dst)[off] = o;
}

// ---------------- GEMM core: 128x256 block tile, BK=64, 16x16x32 MFMA ----------------
// Round-3 verified core (0 bank conflicts, 44.6% MfmaUtil). Round-10's A-direct
// REVERTED (uncoalesced 16-row gather: FETCH 148->315MB, qkv 532us). Round-9 closed
// the pipeline matrix (fine-grained T3 loses at this occupancy regardless of swizzle).
// Round-11 single variable: launch_bounds (256,2)->(256,3). VGPR 108 fits the 170
// budget, LDS 3x48=144<=160KB -> 3 blocks/CU. Mechanism (m114): the 44.6% util is
// capped by ~600cyc/kt of exposed vmcnt(0) stage-drain; a third resident block's
// waves cover it.
__device__ __forceinline__ void gl_lds16(const unsigned short* g, unsigned short* l) {
  __builtin_amdgcn_global_load_lds((const __attribute__((address_space(1))) void*)g,
                                   (__attribute__((address_space(3))) void*)l, 16, 0, 0);
}

// Per wave: 64x128 output = acc[4 m-frags][8 n-frags], 16x16x32 MFMA.
// C-layout (m89-verified): row = quad*4 + reg, col = l16.
__device__ __forceinline__ void gemm_core_wide(const unsigned short* __restrict__ Ab,
                                               const unsigned short* __restrict__ Wb,
                                               unsigned short* lsA, unsigned short* lsB,
                                               f32x4 acc[4][8], int tid) {
  const int lane = tid & 63, wave = tid >> 6;
  const int l16 = lane & 15, quad = lane >> 4;
  const int wr = wave >> 1, wc = wave & 1;
  // swizzle is row-independent at 16-aligned fragment rows: bits 1-2 of row == bits 1-2 of l16
  const int ch = (quad ^ ((l16 >> 1) & 3)) * 8;

  for (int kt = 0; kt < HC / 64; ++kt) {
    __syncthreads();
    // stage A: [2 kh][128 rows][32] = 1024 x 16B chunks; vrow = kh*128 + row
#pragma unroll
    for (int i = 0; i < 4; i++) {
      int c = i * 256 + tid;
      int vrow = c >> 2, slot = c & 3;
      int gc = slot ^ ((vrow >> 1) & 3);
      int row = vrow & 127, kh = vrow >> 7;
      gl_lds16(Ab + (size_t)row * HC + kt * 64 + kh * 32 + gc * 8, lsA + c * 8);
    }
    // stage B: [2 kh][256 rows][32] = 2048 chunks
#pragma unroll
    for (int i = 0; i < 8; i++) {
      int c = i * 256 + tid;
      int vrow = c >> 2, slot = c & 3;
      int gc = slot ^ ((vrow >> 1) & 3);
      int row = vrow & 255, kh = vrow >> 8;
      gl_lds16(Wb + (size_t)row * HC + kt * 64 + kh * 32 + gc * 8, lsB + c * 8);
    }
    __syncthreads();
#pragma unroll
    for (int kh = 0; kh < 2; ++kh) {
      bf16x8 af[4], bfr[8];
#pragma unroll
      for (int mi = 0; mi < 4; mi++) {
        int r = wr * 64 + mi * 16 + l16;
        af[mi] = *(const bf16x8*)(lsA + (kh * 128 + r) * 32 + ch);
      }
#pragma unroll
      for (int nj = 0; nj < 8; nj++) {
        int r = wc * 128 + nj * 16 + l16;
        bfr[nj] = *(const bf16x8*)(lsB + (kh * 256 + r) * 32 + ch);
      }
#pragma unroll
      for (int mi = 0; mi < 4; mi++)
#pragma unroll
        for (int nj = 0; nj < 8; nj++)
          acc[mi][nj] = __builtin_amdgcn_mfma_f32_16x16x32_bf16(af[mi], bfr[nj], acc[mi][nj], 0, 0, 0);
    }
  }
}

// Output projection GEMM: fp32 out [M, 2048]; grid (64, 8)
__global__ __launch_bounds__(256, 3) void gemm_out(const unsigned short* __restrict__ A,
                                                   const unsigned short* __restrict__ W,
                                                   float* __restrict__ outp) {
  __shared__ __align__(16) unsigned short lsA[2 * 128 * 32];
  __shared__ __align__(16) unsigned short lsB[2 * 256 * 32];
  const int tid = threadIdx.x;
  const int lane = tid & 63, wave = tid >> 6;
  const int l16 = lane & 15, quad = lane >> 4;
  const int wr = wave >> 1, wc = wave & 1;
  const int bm = blockIdx.x, bn = blockIdx.y;

  f32x4 acc[4][8];
#pragma unroll
  for (int i = 0; i < 4; i++)
#pragma unroll
    for (int j = 0; j < 8; j++) acc[i][j] = f32x4{0.f, 0.f, 0.f, 0.f};

  gemm_core_wide(A + (size_t)bm * 128 * HC, W + (size_t)bn * 256 * HC, lsA, lsB, acc, tid);

#pragma unroll
  for (int mi = 0; mi < 4; mi++)
#pragma unroll
    for (int nj = 0; nj < 8; nj++) {
      const int n = bn * 256 + wc * 128 + nj * 16 + l16;
#pragma unroll
      for (int rr = 0; rr < 4; rr++) {
        const int m = bm * 128 + wr * 64 + mi * 16 + quad * 4 + rr;
        outp[(size_t)m * HC + n] = acc[mi][nj][rr];
      }
    }
}

// Fused QKV GEMM: grid (64, 24); blockIdx.y>>3 selects {Q,K,V}.
// Q,K -> [B,H,T,D] with RoPE fused; V -> [B,H,D,T] via operand swap (coalesced).
__global__ __launch_bounds__(256, 3) void gemm_qkv(const unsigned short* __restrict__ A,
                                                    const unsigned short* __restrict__ W0,
                                                    const unsigned short* __restrict__ W1,
                                                    const unsigned short* __restrict__ W2,
                                                    unsigned short* __restrict__ Qo,
                                                    unsigned short* __restrict__ Ko,
                                                    unsigned short* __restrict__ Vto) {
  __shared__ __align__(16) unsigned short lsA[2 * 128 * 32];
  __shared__ __align__(16) unsigned short lsB[2 * 256 * 32];
  const int tid = threadIdx.x;
  const int lane = tid & 63, wave = tid >> 6;
  const int l16 = lane & 15, quad = lane >> 4;
  const int wr = wave >> 1, wc = wave & 1;
  const int bm = blockIdx.x;
  const int which = blockIdx.y >> 3;
  const int bn = blockIdx.y & 7;

  f32x4 acc[4][8];
#pragma unroll
  for (int i = 0; i < 4; i++)
#pragma unroll
    for (int j = 0; j < 8; j++) acc[i][j] = f32x4{0.f, 0.f, 0.f, 0.f};

  if (which < 2) {
    const unsigned short* W = (which == 0) ? W0 : W1;
    unsigned short* outp = (which == 0) ? Qo : Ko;
    gemm_core_wide(A + (size_t)bm * 128 * HC, W + (size_t)bn * 256 * HC, lsA, lsB, acc, tid);
    // Wave's 128 cols = one head: h = bn*2 + wc. RoPE pair: acc[mi][nj] (d) with
    // acc[mi][nj+4] (d+64), d = nj*16 + l16, nj in {0..3}.
    const int h = bn * 2 + wc;
#pragma unroll
    for (int nj = 0; nj < 4; nj++) {
      const int dlo = nj * 16 + l16;
      const float invf = __expf((float)dlo * (-0.14391156831212787f));
#pragma unroll
      for (int mi = 0; mi < 4; mi++)
#pragma unroll
        for (int rr = 0; rr < 4; rr++) {
          const int m = bm * 128 + wr * 64 + mi * 16 + quad * 4 + rr;
          const int t = m & 255, b = m >> 8;
          float ang = (float)t * invf;
          float sn, cs;
          __sincosf(ang, &sn, &cs);
          float lo = acc[mi][nj][rr], hi = acc[mi][nj + 4][rr];
          size_t base = (((size_t)b * HH + h) * HT + t) * HD;
          outp[base + dlo] = f2bf(lo * cs - hi * sn);
          outp[base + 64 + dlo] = f2bf(hi * cs + lo * sn);
        }
    }
  } else {
    // V^T: A-operand = wv channel tile (128 ch = one head), B-operand = x token tile (256).
    int v = bn * 64 + bm;            // 512 blocks
    int tok = v & 31, ch2 = v >> 5;  // 32 token-tiles x 16 channel-tiles
    gemm_core_wide(W2 + (size_t)ch2 * 128 * HC, A + (size_t)tok * 256 * HC, lsA, lsB, acc, tid);
    const int b = tok, h = ch2;
#pragma unroll
    for (int mi = 0; mi < 4; mi++)
#pragma unroll
      for (int nj = 0; nj < 8; nj++) {
        const int t = wc * 128 + nj * 16 + l16;
#pragma unroll
        for (int rr = 0; rr < 4; rr++) {
          const int d = wr * 64 + mi * 16 + quad * 4 + rr;
          Vto[(((size_t)b * HH + h) * HD + d) * HT + t] = f2bf(acc[mi][nj][rr]);
        }
      }
  }
}

// ---------------- causal flash attention ----------------
// Round-8 body (K-load batching: ~+18us normalized win). Pairing {3,0}/{2,1} +
// T13 defer-max + ks=0 V-hoist + kf[4][2] batch retained. Do not touch.
__global__ __launch_bounds__(256) void attn_kernel(const unsigned short* __restrict__ Q,
                                                   const unsigned short* __restrict__ K,
                                                   const unsigned short* __restrict__ Vt,
                                                   unsigned short* __restrict__ Y) {
  const int g = blockIdx.x;      // 1024 blocks
  const int bh = g & 511;
  const int pairp = g >> 9;      // 0 -> {3,0}, 1 -> {2,1}
  const int wave = threadIdx.x >> 6;
  const int lane = threadIdx.x & 63;
  const int quad = lane >> 4, l16 = lane & 15;

  const unsigned short* Qh = Q + (size_t)bh * HT * HD;
  const unsigned short* Kh = K + (size_t)bh * HT * HD;
  const unsigned short* Vh = Vt + (size_t)bh * HD * HT;

  __shared__ __align__(16) unsigned short P[4][16 * 72];
  unsigned short* Pw = P[wave];

  const float scale = 0.088388347648318447f;  // 1/sqrt(128)
  const int b = bh >> 4, h = bh & 15;

  for (int half = 0; half < 2; ++half) {
    const int wq = (pairp == 0) ? (half == 0 ? 3 : 0) : (half == 0 ? 2 : 1);
    const int qrow = wq * 64 + wave * 16;

    bf16x8 qf[4];
#pragma unroll
    for (int ks = 0; ks < 4; ks++)
      qf[ks] = *(const bf16x8*)(Qh + (size_t)(qrow + l16) * HD + ks * 32 + quad * 8);

    f32x4 o[8];
#pragma unroll
    for (int di = 0; di < 8; di++) o[di] = f32x4{0.f, 0.f, 0.f, 0.f};
    float mrow[4], lrow[4];
#pragma unroll
    for (int r = 0; r < 4; r++) { mrow[r] = -1e30f; lrow[r] = 0.f; }

    for (int ct = 0; ct <= wq; ++ct) {
      f32x4 s[4];
#pragma unroll
      for (int ni = 0; ni < 4; ni++) s[ni] = f32x4{0.f, 0.f, 0.f, 0.f};
      const int nimax = (ct == wq) ? wave : 3;
      // QK^T in two half-K batches: issue 8 independent K loads, then 8 MFMAs.
#pragma unroll
      for (int ksh = 0; ksh < 2; ksh++) {
        bf16x8 kf[4][2];
#pragma unroll
        for (int ni = 0; ni < 4; ni++)
          if (ni <= nimax)
#pragma unroll
            for (int k2 = 0; k2 < 2; k2++)
              kf[ni][k2] = *(const bf16x8*)(Kh + (size_t)(ct * 64 + ni * 16 + l16) * HD +
                                            (ksh * 2 + k2) * 32 + quad * 8);
#pragma unroll
        for (int k2 = 0; k2 < 2; k2++)
#pragma unroll
          for (int ni = 0; ni < 4; ni++)
            if (ni <= nimax)
              s[ni] = __builtin_amdgcn_mfma_f32_16x16x32_bf16(qf[ksh * 2 + k2], kf[ni][k2],
                                                              s[ni], 0, 0, 0);
      }
      // T14 hoist: issue ks=0 half of the V tile now; latency hides under softmax.
      bf16x8 vf0[8];
#pragma unroll
      for (int di = 0; di < 8; di++)
        vf0[di] = *(const bf16x8*)(Vh + (size_t)(di * 16 + l16) * HT + ct * 64 + quad * 8);

      if (ct == wq) {
#pragma unroll
        for (int ni = 0; ni < 4; ni++)
#pragma unroll
          for (int r = 0; r < 4; r++) {
            int qr = wave * 16 + quad * 4 + r;
            int kc = ni * 16 + l16;
            s[ni][r] = (kc <= qr) ? s[ni][r] * scale : -1e30f;
          }
      } else {
#pragma unroll
        for (int ni = 0; ni < 4; ni++)
#pragma unroll
          for (int r = 0; r < 4; r++) s[ni][r] *= scale;
      }
      // per-row max (uniform within 16-lane group)
      float pm[4];
#pragma unroll
      for (int r = 0; r < 4; r++) {
        float v = fmaxf(fmaxf(s[0][r], s[1][r]), fmaxf(s[2][r], s[3][r]));
        v = fmaxf(v, __shfl_xor(v, 1, 64));
        v = fmaxf(v, __shfl_xor(v, 2, 64));
        v = fmaxf(v, __shfl_xor(v, 4, 64));
        v = fmaxf(v, __shfl_xor(v, 8, 64));
        pm[r] = v;
      }
      // T13 defer-max: wave-uniform rescale test (max growth across all 16 rows)
      float ex = fmaxf(fmaxf(pm[0] - mrow[0], pm[1] - mrow[1]),
                       fmaxf(pm[2] - mrow[2], pm[3] - mrow[3]));
      ex = fmaxf(ex, __shfl_xor(ex, 16, 64));
      ex = fmaxf(ex, __shfl_xor(ex, 32, 64));
      if (ex > 8.f) {
#pragma unroll
        for (int r = 0; r < 4; r++) {
          float mnew = fmaxf(mrow[r], pm[r]);
          float alpha = __expf(mrow[r] - mnew);
          mrow[r] = mnew;
          lrow[r] *= alpha;
#pragma unroll
          for (int di = 0; di < 8; di++) o[di][r] *= alpha;
        }
      }
#pragma unroll
      for (int r = 0; r < 4; r++) {
        float rs = 0.f;
#pragma unroll
        for (int ni = 0; ni < 4; ni++) {
          float e = __expf(s[ni][r] - mrow[r]);
          s[ni][r] = e;
          rs += e;
        }
        rs += __shfl_xor(rs, 1, 64);
        rs += __shfl_xor(rs, 2, 64);
        rs += __shfl_xor(rs, 4, 64);
        rs += __shfl_xor(rs, 8, 64);
        lrow[r] += rs;
      }
#pragma unroll
      for (int ni = 0; ni < 4; ni++)
#pragma unroll
        for (int r = 0; r < 4; r++)
          Pw[(quad * 4 + r) * 72 + ni * 16 + l16] = f2bf(s[ni][r]);
      // PV: ks=0 uses the hoisted vf0; ks=1 loads inline.
      {
        bf16x8 pf = *(const bf16x8*)(Pw + (size_t)l16 * 72 + quad * 8);
#pragma unroll
        for (int di = 0; di < 8; di++)
          o[di] = __builtin_amdgcn_mfma_f32_16x16x32_bf16(pf, vf0[di], o[di], 0, 0, 0);
      }
      {
        bf16x8 pf = *(const bf16x8*)(Pw + (size_t)l16 * 72 + 32 + quad * 8);
#pragma unroll
        for (int di = 0; di < 8; di++) {
          bf16x8 vf = *(const bf16x8*)(Vh + (size_t)(di * 16 + l16) * HT + ct * 64 + 32 + quad * 8);
          o[di] = __builtin_amdgcn_mfma_f32_16x16x32_bf16(pf, vf, o[di], 0, 0, 0);
        }
      }
    }

#pragma unroll
    for (int r = 0; r < 4; r++) {
      float inv = 1.f / lrow[r];
      int t = qrow + quad * 4 + r;
      size_t rowb = ((size_t)b * HT + t) * HC + h * HD;
#pragma unroll
      for (int di = 0; di < 8; di++)
        Y[rowb + di * 16 + l16] = f2bf(o[di][r] * inv);
    }
  }
}

// ---------------- launch ----------------
extern "C" void kernel_launch(void* const* d_in, const int* in_sizes, int n_in,
                              void* d_out, int out_size, void* d_ws, size_t ws_size,
                              hipStream_t stream) {
  const float* x  = (const float*)d_in[0];
  const float* wq = (const float*)d_in[1];
  const float* wk = (const float*)d_in[2];
  const float* wv = (const float*)d_in[3];
  const float* wo = (const float*)d_in[4];
  float* out = (float*)d_out;

  char* ws = (char*)d_ws;
  const size_t MB = (size_t)1 << 20;
  unsigned short* wqb = (unsigned short*)(ws + 0 * MB);
  unsigned short* wkb = (unsigned short*)(ws + 8 * MB);
  unsigned short* wvb = (unsigned short*)(ws + 16 * MB);
  unsigned short* wob = (unsigned short*)(ws + 24 * MB);
  unsigned short* xb  = (unsigned short*)(ws + 32 * MB);
  unsigned short* Qb  = (unsigned short*)(ws + 64 * MB);
  unsigned short* Kb  = (unsigned short*)(ws + 96 * MB);
  unsigned short* Vtb = (unsigned short*)(ws + 128 * MB);
  unsigned short* Yb  = xb;  // reuse x's bf16 buffer after QKV GEMMs

  cvt_all<<<32768, 256, 0, stream>>>(x, wq, wk, wv, wo, xb, wqb, wkb, wvb, wob);

  gemm_qkv<<<dim3(HM / 128, 24), 256, 0, stream>>>(xb, wqb, wkb, wvb, Qb, Kb, Vtb);

  attn_kernel<<<1024, 256, 0, stream>>>(Qb, Kb, Vtb, Yb);

  gemm_out<<<dim3(HM / 128, HC / 256), 256, 0, stream>>>(Yb, wob, out);
}

// Round 12
// 487.151 us; speedup vs baseline: 1.8551x; 1.5843x over previous
//
#include <hip/hip_runtime.h>

#define HB 32
#define HT 256
#define HC 2048
#define HH 16
#define HD 128
#define HM (HB * HT)  // 8192

typedef __bf16 bf16x8 __attribute__((ext_vector_type(8)));
typedef float f32x4 __attribute__((ext_vector_type(4)));

__device__ __forceinline__ unsigned short f2bf(float f) {
  unsigned u = __float_as_uint(f);
  u += 0x7FFFu + ((u >> 16) & 1u);  // round-to-nearest-even
  return (unsigned short)(u >> 16);
}

// ---------------- fused fp32 -> bf16 convert (x + 4 weights) ----------------
__global__ __launch_bounds__(256) void cvt_all(
    const float* __restrict__ x, const float* __restrict__ wq, const float* __restrict__ wk,
    const float* __restrict__ wv, const float* __restrict__ wo,
    unsigned short* __restrict__ xb, unsigned short* __restrict__ wqb,
    unsigned short* __restrict__ wkb, unsigned short* __restrict__ wvb,
    unsigned short* __restrict__ wob) {
  size_t i = (size_t)blockIdx.x * 256 + threadIdx.x;
  const float* src;
  unsigned short* dst;
  size_t off;
  if (i < 4194304) {
    src = x; dst = xb; off = i;
  } else {
    size_t j = i - 4194304;
    int w = (int)(j >> 20);
    off = j & 1048575;
    src = (w == 0) ? wq : (w == 1) ? wk : (w == 2) ? wv : wo;
    dst = (w == 0) ? wqb : (w == 1) ? wkb : (w == 2) ? wvb : wob;
  }
  float4 v = ((const float4*)src)[off];
  ushort4 o;
  o.x = f2bf(v.x); o.y = f2bf(v.y); o.z = f2bf(v.z); o.w = f2bf(v.w);
  ((ushort4*)dst)[off] = o;
}

// ---------------- GEMM core: 128x256 block tile, BK=64, 16x16x32 MFMA ----------------
// FINAL GEMM structure (matrix closed over rounds 0-11):
//   - round-3 2-barrier core, 0 bank conflicts, 44.6% MfmaUtil, ~205us for 3 GEMMs.
//   - fine-grained pipeline (T3/T4/T5): loses at any swizzle (r1 41%->r2 35%->r9 37.5%).
//   - A-direct-from-global: uncoalesced 16-row gather, FETCH 148->315MB (r10, 532us).
//   - 3 blocks/CU: VGPR squeeze 108->84 + L2 panel-reuse collapse, FETCH x2 (r11, 434us).
// (256,2) is the verified sweet spot. DO NOT TOUCH.
__device__ __forceinline__ void gl_lds16(const unsigned short* g, unsigned short* l) {
  __builtin_amdgcn_global_load_lds((const __attribute__((address_space(1))) void*)g,
                                   (__attribute__((address_space(3))) void*)l, 16, 0, 0);
}

// Per wave: 64x128 output = acc[4 m-frags][8 n-frags], 16x16x32 MFMA.
// C-layout (m89-verified): row = quad*4 + reg, col = l16.
__device__ __forceinline__ void gemm_core_wide(const unsigned short* __restrict__ Ab,
                                               const unsigned short* __restrict__ Wb,
                                               unsigned short* lsA, unsigned short* lsB,
                                               f32x4 acc[4][8], int tid) {
  const int lane = tid & 63, wave = tid >> 6;
  const int l16 = lane & 15, quad = lane >> 4;
  const int wr = wave >> 1, wc = wave & 1;
  // swizzle is row-independent at 16-aligned fragment rows: bits 1-2 of row == bits 1-2 of l16
  const int ch = (quad ^ ((l16 >> 1) & 3)) * 8;

  for (int kt = 0; kt < HC / 64; ++kt) {
    __syncthreads();
    // stage A: [2 kh][128 rows][32] = 1024 x 16B chunks; vrow = kh*128 + row
#pragma unroll
    for (int i = 0; i < 4; i++) {
      int c = i * 256 + tid;
      int vrow = c >> 2, slot = c & 3;
      int gc = slot ^ ((vrow >> 1) & 3);
      int row = vrow & 127, kh = vrow >> 7;
      gl_lds16(Ab + (size_t)row * HC + kt * 64 + kh * 32 + gc * 8, lsA + c * 8);
    }
    // stage B: [2 kh][256 rows][32] = 2048 chunks
#pragma unroll
    for (int i = 0; i < 8; i++) {
      int c = i * 256 + tid;
      int vrow = c >> 2, slot = c & 3;
      int gc = slot ^ ((vrow >> 1) & 3);
      int row = vrow & 255, kh = vrow >> 8;
      gl_lds16(Wb + (size_t)row * HC + kt * 64 + kh * 32 + gc * 8, lsB + c * 8);
    }
    __syncthreads();
#pragma unroll
    for (int kh = 0; kh < 2; ++kh) {
      bf16x8 af[4], bfr[8];
#pragma unroll
      for (int mi = 0; mi < 4; mi++) {
        int r = wr * 64 + mi * 16 + l16;
        af[mi] = *(const bf16x8*)(lsA + (kh * 128 + r) * 32 + ch);
      }
#pragma unroll
      for (int nj = 0; nj < 8; nj++) {
        int r = wc * 128 + nj * 16 + l16;
        bfr[nj] = *(const bf16x8*)(lsB + (kh * 256 + r) * 32 + ch);
      }
#pragma unroll
      for (int mi = 0; mi < 4; mi++)
#pragma unroll
        for (int nj = 0; nj < 8; nj++)
          acc[mi][nj] = __builtin_amdgcn_mfma_f32_16x16x32_bf16(af[mi], bfr[nj], acc[mi][nj], 0, 0, 0);
    }
  }
}

// Output projection GEMM: fp32 out [M, 2048]; grid (64, 8)
__global__ __launch_bounds__(256, 2) void gemm_out(const unsigned short* __restrict__ A,
                                                   const unsigned short* __restrict__ W,
                                                   float* __restrict__ outp) {
  __shared__ __align__(16) unsigned short lsA[2 * 128 * 32];
  __shared__ __align__(16) unsigned short lsB[2 * 256 * 32];
  const int tid = threadIdx.x;
  const int lane = tid & 63, wave = tid >> 6;
  const int l16 = lane & 15, quad = lane >> 4;
  const int wr = wave >> 1, wc = wave & 1;
  const int bm = blockIdx.x, bn = blockIdx.y;

  f32x4 acc[4][8];
#pragma unroll
  for (int i = 0; i < 4; i++)
#pragma unroll
    for (int j = 0; j < 8; j++) acc[i][j] = f32x4{0.f, 0.f, 0.f, 0.f};

  gemm_core_wide(A + (size_t)bm * 128 * HC, W + (size_t)bn * 256 * HC, lsA, lsB, acc, tid);

#pragma unroll
  for (int mi = 0; mi < 4; mi++)
#pragma unroll
    for (int nj = 0; nj < 8; nj++) {
      const int n = bn * 256 + wc * 128 + nj * 16 + l16;
#pragma unroll
      for (int rr = 0; rr < 4; rr++) {
        const int m = bm * 128 + wr * 64 + mi * 16 + quad * 4 + rr;
        outp[(size_t)m * HC + n] = acc[mi][nj][rr];
      }
    }
}

// Fused QKV GEMM: grid (64, 24); blockIdx.y>>3 selects {Q,K,V}.
// Q,K -> [B,H,T,D] with RoPE fused; V -> [B,H,D,T] via operand swap (coalesced).
__global__ __launch_bounds__(256, 2) void gemm_qkv(const unsigned short* __restrict__ A,
                                                    const unsigned short* __restrict__ W0,
                                                    const unsigned short* __restrict__ W1,
                                                    const unsigned short* __restrict__ W2,
                                                    unsigned short* __restrict__ Qo,
                                                    unsigned short* __restrict__ Ko,
                                                    unsigned short* __restrict__ Vto) {
  __shared__ __align__(16) unsigned short lsA[2 * 128 * 32];
  __shared__ __align__(16) unsigned short lsB[2 * 256 * 32];
  const int tid = threadIdx.x;
  const int lane = tid & 63, wave = tid >> 6;
  const int l16 = lane & 15, quad = lane >> 4;
  const int wr = wave >> 1, wc = wave & 1;
  const int bm = blockIdx.x;
  const int which = blockIdx.y >> 3;
  const int bn = blockIdx.y & 7;

  f32x4 acc[4][8];
#pragma unroll
  for (int i = 0; i < 4; i++)
#pragma unroll
    for (int j = 0; j < 8; j++) acc[i][j] = f32x4{0.f, 0.f, 0.f, 0.f};

  if (which < 2) {
    const unsigned short* W = (which == 0) ? W0 : W1;
    unsigned short* outp = (which == 0) ? Qo : Ko;
    gemm_core_wide(A + (size_t)bm * 128 * HC, W + (size_t)bn * 256 * HC, lsA, lsB, acc, tid);
    // Wave's 128 cols = one head: h = bn*2 + wc. RoPE pair: acc[mi][nj] (d) with
    // acc[mi][nj+4] (d+64), d = nj*16 + l16, nj in {0..3}.
    const int h = bn * 2 + wc;
#pragma unroll
    for (int nj = 0; nj < 4; nj++) {
      const int dlo = nj * 16 + l16;
      const float invf = __expf((float)dlo * (-0.14391156831212787f));
#pragma unroll
      for (int mi = 0; mi < 4; mi++)
#pragma unroll
        for (int rr = 0; rr < 4; rr++) {
          const int m = bm * 128 + wr * 64 + mi * 16 + quad * 4 + rr;
          const int t = m & 255, b = m >> 8;
          float ang = (float)t * invf;
          float sn, cs;
          __sincosf(ang, &sn, &cs);
          float lo = acc[mi][nj][rr], hi = acc[mi][nj + 4][rr];
          size_t base = (((size_t)b * HH + h) * HT + t) * HD;
          outp[base + dlo] = f2bf(lo * cs - hi * sn);
          outp[base + 64 + dlo] = f2bf(hi * cs + lo * sn);
        }
    }
  } else {
    // V^T: A-operand = wv channel tile (128 ch = one head), B-operand = x token tile (256).
    int v = bn * 64 + bm;            // 512 blocks
    int tok = v & 31, ch2 = v >> 5;  // 32 token-tiles x 16 channel-tiles
    gemm_core_wide(W2 + (size_t)ch2 * 128 * HC, A + (size_t)tok * 256 * HC, lsA, lsB, acc, tid);
    const int b = tok, h = ch2;
#pragma unroll
    for (int mi = 0; mi < 4; mi++)
#pragma unroll
      for (int nj = 0; nj < 8; nj++) {
        const int t = wc * 128 + nj * 16 + l16;
#pragma unroll
        for (int rr = 0; rr < 4; rr++) {
          const int d = wr * 64 + mi * 16 + quad * 4 + rr;
          Vto[(((size_t)b * HH + h) * HD + d) * HT + t] = f2bf(acc[mi][nj][rr]);
        }
      }
  }
}

// ---------------- causal flash attention ----------------
// Round-8 body + full V-tile hoist. All three attn wins (K-batch r8, vf0 hoist r6,
// pairing r6) are "batch independent L2 loads ahead of dependent work"; vf1 completes
// the pattern: whole V tile (64 VGPR transient) issued before softmax, PV is then
// pure-register MFMA. VGPR ~84+32 = ~116 <= 128 (no occupancy cliff; 4 blocks/CU).
// T13 defer-max retained.
__global__ __launch_bounds__(256) void attn_kernel(const unsigned short* __restrict__ Q,
                                                   const unsigned short* __restrict__ K,
                                                   const unsigned short* __restrict__ Vt,
                                                   unsigned short* __restrict__ Y) {
  const int g = blockIdx.x;      // 1024 blocks
  const int bh = g & 511;
  const int pairp = g >> 9;      // 0 -> {3,0}, 1 -> {2,1}
  const int wave = threadIdx.x >> 6;
  const int lane = threadIdx.x & 63;
  const int quad = lane >> 4, l16 = lane & 15;

  const unsigned short* Qh = Q + (size_t)bh * HT * HD;
  const unsigned short* Kh = K + (size_t)bh * HT * HD;
  const unsigned short* Vh = Vt + (size_t)bh * HD * HT;

  __shared__ __align__(16) unsigned short P[4][16 * 72];
  unsigned short* Pw = P[wave];

  const float scale = 0.088388347648318447f;  // 1/sqrt(128)
  const int b = bh >> 4, h = bh & 15;

  for (int half = 0; half < 2; ++half) {
    const int wq = (pairp == 0) ? (half == 0 ? 3 : 0) : (half == 0 ? 2 : 1);
    const int qrow = wq * 64 + wave * 16;

    bf16x8 qf[4];
#pragma unroll
    for (int ks = 0; ks < 4; ks++)
      qf[ks] = *(const bf16x8*)(Qh + (size_t)(qrow + l16) * HD + ks * 32 + quad * 8);

    f32x4 o[8];
#pragma unroll
    for (int di = 0; di < 8; di++) o[di] = f32x4{0.f, 0.f, 0.f, 0.f};
    float mrow[4], lrow[4];
#pragma unroll
    for (int r = 0; r < 4; r++) { mrow[r] = -1e30f; lrow[r] = 0.f; }

    for (int ct = 0; ct <= wq; ++ct) {
      f32x4 s[4];
#pragma unroll
      for (int ni = 0; ni < 4; ni++) s[ni] = f32x4{0.f, 0.f, 0.f, 0.f};
      const int nimax = (ct == wq) ? wave : 3;
      // QK^T in two half-K batches: issue 8 independent K loads, then 8 MFMAs.
#pragma unroll
      for (int ksh = 0; ksh < 2; ksh++) {
        bf16x8 kf[4][2];
#pragma unroll
        for (int ni = 0; ni < 4; ni++)
          if (ni <= nimax)
#pragma unroll
            for (int k2 = 0; k2 < 2; k2++)
              kf[ni][k2] = *(const bf16x8*)(Kh + (size_t)(ct * 64 + ni * 16 + l16) * HD +
                                            (ksh * 2 + k2) * 32 + quad * 8);
#pragma unroll
        for (int k2 = 0; k2 < 2; k2++)
#pragma unroll
          for (int ni = 0; ni < 4; ni++)
            if (ni <= nimax)
              s[ni] = __builtin_amdgcn_mfma_f32_16x16x32_bf16(qf[ksh * 2 + k2], kf[ni][k2],
                                                              s[ni], 0, 0, 0);
      }
      // T14 hoist: issue the WHOLE V tile now; latency hides under softmax.
      bf16x8 vf0[8], vf1[8];
#pragma unroll
      for (int di = 0; di < 8; di++)
        vf0[di] = *(const bf16x8*)(Vh + (size_t)(di * 16 + l16) * HT + ct * 64 + quad * 8);
#pragma unroll
      for (int di = 0; di < 8; di++)
        vf1[di] = *(const bf16x8*)(Vh + (size_t)(di * 16 + l16) * HT + ct * 64 + 32 + quad * 8);

      if (ct == wq) {
#pragma unroll
        for (int ni = 0; ni < 4; ni++)
#pragma unroll
          for (int r = 0; r < 4; r++) {
            int qr = wave * 16 + quad * 4 + r;
            int kc = ni * 16 + l16;
            s[ni][r] = (kc <= qr) ? s[ni][r] * scale : -1e30f;
          }
      } else {
#pragma unroll
        for (int ni = 0; ni < 4; ni++)
#pragma unroll
          for (int r = 0; r < 4; r++) s[ni][r] *= scale;
      }
      // per-row max (uniform within 16-lane group)
      float pm[4];
#pragma unroll
      for (int r = 0; r < 4; r++) {
        float v = fmaxf(fmaxf(s[0][r], s[1][r]), fmaxf(s[2][r], s[3][r]));
        v = fmaxf(v, __shfl_xor(v, 1, 64));
        v = fmaxf(v, __shfl_xor(v, 2, 64));
        v = fmaxf(v, __shfl_xor(v, 4, 64));
        v = fmaxf(v, __shfl_xor(v, 8, 64));
        pm[r] = v;
      }
      // T13 defer-max: wave-uniform rescale test (max growth across all 16 rows)
      float ex = fmaxf(fmaxf(pm[0] - mrow[0], pm[1] - mrow[1]),
                       fmaxf(pm[2] - mrow[2], pm[3] - mrow[3]));
      ex = fmaxf(ex, __shfl_xor(ex, 16, 64));
      ex = fmaxf(ex, __shfl_xor(ex, 32, 64));
      if (ex > 8.f) {
#pragma unroll
        for (int r = 0; r < 4; r++) {
          float mnew = fmaxf(mrow[r], pm[r]);
          float alpha = __expf(mrow[r] - mnew);
          mrow[r] = mnew;
          lrow[r] *= alpha;
#pragma unroll
          for (int di = 0; di < 8; di++) o[di][r] *= alpha;
        }
      }
#pragma unroll
      for (int r = 0; r < 4; r++) {
        float rs = 0.f;
#pragma unroll
        for (int ni = 0; ni < 4; ni++) {
          float e = __expf(s[ni][r] - mrow[r]);
          s[ni][r] = e;
          rs += e;
        }
        rs += __shfl_xor(rs, 1, 64);
        rs += __shfl_xor(rs, 2, 64);
        rs += __shfl_xor(rs, 4, 64);
        rs += __shfl_xor(rs, 8, 64);
        lrow[r] += rs;
      }
#pragma unroll
      for (int ni = 0; ni < 4; ni++)
#pragma unroll
        for (int r = 0; r < 4; r++)
          Pw[(quad * 4 + r) * 72 + ni * 16 + l16] = f2bf(s[ni][r]);
      // PV: both halves from hoisted registers (no inline loads).
      {
        bf16x8 pf = *(const bf16x8*)(Pw + (size_t)l16 * 72 + quad * 8);
#pragma unroll
        for (int di = 0; di < 8; di++)
          o[di] = __builtin_amdgcn_mfma_f32_16x16x32_bf16(pf, vf0[di], o[di], 0, 0, 0);
      }
      {
        bf16x8 pf = *(const bf16x8*)(Pw + (size_t)l16 * 72 + 32 + quad * 8);
#pragma unroll
        for (int di = 0; di < 8; di++)
          o[di] = __builtin_amdgcn_mfma_f32_16x16x32_bf16(pf, vf1[di], o[di], 0, 0, 0);
      }
    }

#pragma unroll
    for (int r = 0; r < 4; r++) {
      float inv = 1.f / lrow[r];
      int t = qrow + quad * 4 + r;
      size_t rowb = ((size_t)b * HT + t) * HC + h * HD;
#pragma unroll
      for (int di = 0; di < 8; di++)
        Y[rowb + di * 16 + l16] = f2bf(o[di][r] * inv);
    }
  }
}

// ---------------- launch ----------------
extern "C" void kernel_launch(void* const* d_in, const int* in_sizes, int n_in,
                              void* d_out, int out_size, void* d_ws, size_t ws_size,
                              hipStream_t stream) {
  const float* x  = (const float*)d_in[0];
  const float* wq = (const float*)d_in[1];
  const float* wk = (const float*)d_in[2];
  const float* wv = (const float*)d_in[3];
  const float* wo = (const float*)d_in[4];
  float* out = (float*)d_out;

  char* ws = (char*)d_ws;
  const size_t MB = (size_t)1 << 20;
  unsigned short* wqb = (unsigned short*)(ws + 0 * MB);
  unsigned short* wkb = (unsigned short*)(ws + 8 * MB);
  unsigned short* wvb = (unsigned short*)(ws + 16 * MB);
  unsigned short* wob = (unsigned short*)(ws + 24 * MB);
  unsigned short* xb  = (unsigned short*)(ws + 32 * MB);
  unsigned short* Qb  = (unsigned short*)(ws + 64 * MB);
  unsigned short* Kb  = (unsigned short*)(ws + 96 * MB);
  unsigned short* Vtb = (unsigned short*)(ws + 128 * MB);
  unsigned short* Yb  = xb;  // reuse x's bf16 buffer after QKV GEMMs

  cvt_all<<<32768, 256, 0, stream>>>(x, wq, wk, wv, wo, xb, wqb, wkb, wvb, wob);

  gemm_qkv<<<dim3(HM / 128, 24), 256, 0, stream>>>(xb, wqb, wkb, wvb, Qb, Kb, Vtb);

  attn_kernel<<<1024, 256, 0, stream>>>(Qb, Kb, Vtb, Yb);

  gemm_out<<<dim3(HM / 128, HC / 256), 256, 0, stream>>>(Yb, wob, out);
}